// Round 6
// baseline (341.887 us; speedup 1.0000x reference)
//
#include <hip/hip_runtime.h>

// Problem constants (B=8, T=4096, C=512)
#define BB 8
#define TT 4096
#define CC 512
#define MM (BB * TT)   // 32768 rows
#define SS 128         // scan chunks
#define LL 32          // steps per chunk (SS*LL == TT)

typedef short short8 __attribute__((ext_vector_type(8)));
typedef unsigned short ushort8 __attribute__((ext_vector_type(8)));
typedef float f32x4 __attribute__((ext_vector_type(4)));

__device__ __forceinline__ unsigned short f2bf(float f) {
    unsigned int u = __float_as_uint(f);
    u += 0x7FFFu + ((u >> 16) & 1u);   // RNE
    return (unsigned short)(u >> 16);
}
__device__ __forceinline__ float bf2f(unsigned short h) {
    return __uint_as_float(((unsigned int)h) << 16);
}

// async global->LDS, 16B per lane. LDS dest must be wave-uniform base + lane*16.
__device__ __forceinline__ void gl_lds16(const void* g, void* l) {
    __builtin_amdgcn_global_load_lds(
        (__attribute__((address_space(1))) void*)(unsigned long long)g,
        (__attribute__((address_space(3))) void*)(unsigned int)(unsigned long long)l,
        16, 0, 0);
}

__device__ __forceinline__ ushort8 pack8(f32x4 a, f32x4 b) {
    ushort8 r;
    r[0] = f2bf(a.x); r[1] = f2bf(a.y); r[2] = f2bf(a.z); r[3] = f2bf(a.w);
    r[4] = f2bf(b.x); r[5] = f2bf(b.y); r[6] = f2bf(b.z); r[7] = f2bf(b.w);
    return r;
}

// ---------------------------------------------------------------------------
// Kernel 1: prep.
//  blocks [0, NXB)              : xb = bf16(x)                   (coalesced)
//  blocks [NXB, NXB+NWB)        : folded weights w1T/w2T:
//        w1T[which][n][k] = bf16(mix_which[k]      * w_which[k][n])
//        w2T[which][n][k] = bf16((1-mix_which[k])  * w_which[k][n])
//  blocks [NXB+NWB, +NOB)       : woT[n][k] = bf16(wo[k][n])
//  last block                   : zero page
// ---------------------------------------------------------------------------
#define NXB (MM * CC / 8 / 256)          // 8192
#define NWB (3 * CC * CC / 8 / 256)      // 384
#define NOB (CC * CC / 8 / 256)          // 128

__global__ __launch_bounds__(256) void prep(
    const float* __restrict__ x,
    const float* __restrict__ mixk, const float* __restrict__ mixv,
    const float* __restrict__ mixr,
    const float* __restrict__ wk, const float* __restrict__ wv,
    const float* __restrict__ wr, const float* __restrict__ wo,
    unsigned short* __restrict__ xb,
    unsigned short* __restrict__ w1T, unsigned short* __restrict__ w2T,
    unsigned short* __restrict__ woT, unsigned short* __restrict__ zp) {
    const int blk = blockIdx.x;
    const int tid = threadIdx.x;
    if (blk < NXB) {
        const size_t e0 = ((size_t)blk * 256 + tid) * 8;
        f32x4 a = ((const f32x4*)(x + e0))[0];
        f32x4 b = ((const f32x4*)(x + e0))[1];
        *(ushort8*)(xb + e0) = pack8(a, b);
    } else if (blk < NXB + NWB) {
        // idx over 3*512*64 (which, n, kgroup)
        const int idx = (blk - NXB) * 256 + tid;
        const int kg = idx & 63;             // k-group of 8
        const int n  = (idx >> 6) & (CC - 1);
        const int which = idx >> 15;
        const float* w = (which == 0) ? wk : (which == 1) ? wv : wr;
        const float* m = (which == 0) ? mixk : (which == 1) ? mixv : mixr;
        const size_t o = (size_t)which * CC * CC + (size_t)n * CC + kg * 8;
#pragma unroll
        for (int j = 0; j < 8; ++j) {
            const int k = kg * 8 + j;
            const float wv_ = w[(size_t)k * CC + n];
            const float mv_ = m[k];
            w1T[o + j] = f2bf(mv_ * wv_);
            w2T[o + j] = f2bf((1.0f - mv_) * wv_);
        }
    } else if (blk < NXB + NWB + NOB) {
        const int idx = (blk - NXB - NWB) * 256 + tid;
        const int kg = idx & 63;
        const int n  = idx >> 6;
#pragma unroll
        for (int j = 0; j < 8; ++j) {
            const int k = kg * 8 + j;
            woT[(size_t)n * CC + kg * 8 + j] = f2bf(wo[(size_t)k * CC + n]);
        }
    } else {
        if (tid < 128) zp[tid] = 0;          // 256B zero page
    }
}

// ---------------------------------------------------------------------------
// Kernel 2: fused mix+GEMM for all of k, v, sr in ONE dispatch.
//   C_which[m] = xb[m] @ W1_which + xb[m-1] @ W2_which   (xb[-1 per batch]=0)
// Tile: 256 rows x 128 cols. A staged as a 257-row x 32 window (x and xshift
// share it at +/-1 row). 4 waves, each 64 rows x 128 cols = 4x8 frags,
// 64 MFMA per wave per kt. grid=(pm=128, pn=12), pm fastest => consecutive
// blocks share the same W-slab in L2.
// ---------------------------------------------------------------------------
__global__ __launch_bounds__(256, 2) void gemm_kvr3(
    const unsigned short* __restrict__ xb,
    const unsigned short* __restrict__ w1T, const unsigned short* __restrict__ w2T,
    const unsigned short* __restrict__ zp,
    unsigned short* __restrict__ kb, unsigned short* __restrict__ vb,
    unsigned short* __restrict__ srb) {
    __shared__ unsigned short As[257 * 32];   // 16448 B
    __shared__ unsigned short B1s[128 * 32];  //  8192 B
    __shared__ unsigned short B2s[128 * 32];  //  8192 B

    const int tid = threadIdx.x;
    const int pm = blockIdx.x;                 // 0..127
    const int pn = blockIdx.y;                 // 0..11
    const int which = pn >> 2;
    const int nslab = pn & 3;
    const int m0 = pm * 256;
    const bool bound = ((pm & 15) == 0);       // tile contains a t==0 row

    const unsigned short* W1 = w1T + (size_t)which * CC * CC + (size_t)nslab * 128 * CC;
    const unsigned short* W2 = w2T + (size_t)which * CC * CC + (size_t)nslab * 128 * CC;

    // A staging: window rows 0..256 <-> global rows m0-1 .. m0+255.
    // seg s = r*256 + tid (r=0..3): row = s>>2, colgroup = s&3; tail segs
    // 1024..1027 (row 256) by tid<4.
    const int arow = tid >> 2;                 // row offset within round
    const int acg  = tid & 3;
    const unsigned short* agA[4];
#pragma unroll
    for (int r = 0; r < 4; ++r)
        agA[r] = xb + (size_t)(m0 - 1 + r * 64 + arow) * CC + acg * 8;
    if (bound && tid < 4) agA[0] = zp + tid * 8;   // row 0 -> zeros (t==0 xshift)
    const unsigned short* agT = xb + (size_t)(m0 + 255) * CC + (tid & 3) * 8; // tail row 256
    const unsigned short* bg1 = W1 + (size_t)(tid >> 2) * CC + (tid & 3) * 8; // rows 0..63
    const unsigned short* bg2 = W2 + (size_t)(tid >> 2) * CC + (tid & 3) * 8;

    const int wv = tid >> 6, lane = tid & 63;
    const int q = lane >> 4, l16 = lane & 15;

    f32x4 acc[4][8];
#pragma unroll
    for (int i = 0; i < 4; i++)
#pragma unroll
        for (int j = 0; j < 8; j++) acc[i][j] = (f32x4){0.f, 0.f, 0.f, 0.f};

    for (int kt = 0; kt < 16; ++kt) {
        const int k0 = kt * 32;
#pragma unroll
        for (int r = 0; r < 4; ++r)
            gl_lds16(agA[r] + k0, &As[(r * 256 + tid) * 8]);
        if (tid < 4)
            gl_lds16(agT + k0, &As[(1024 + tid) * 8]);
#pragma unroll
        for (int r = 0; r < 2; ++r) {
            gl_lds16(bg1 + (size_t)r * 64 * CC + k0, &B1s[(r * 256 + tid) * 8]);
            gl_lds16(bg2 + (size_t)r * 64 * CC + k0, &B2s[(r * 256 + tid) * 8]);
        }

        __syncthreads();

        short8 ax[4], axx[4], b1[8], b2[8];
#pragma unroll
        for (int i = 0; i < 4; i++) {
            const int rr = wv * 64 + i * 16 + l16;
            ax[i]  = *(const short8*)&As[(rr + 1) * 32 + q * 8];
            axx[i] = *(const short8*)&As[rr * 32 + q * 8];
        }
#pragma unroll
        for (int j = 0; j < 8; j++) {
            b1[j] = *(const short8*)&B1s[(j * 16 + l16) * 32 + q * 8];
            b2[j] = *(const short8*)&B2s[(j * 16 + l16) * 32 + q * 8];
        }
#pragma unroll
        for (int i = 0; i < 4; i++)
#pragma unroll
            for (int j = 0; j < 8; j++) {
                acc[i][j] = __builtin_amdgcn_mfma_f32_16x16x32_bf16(ax[i],  b1[j], acc[i][j], 0, 0, 0);
                acc[i][j] = __builtin_amdgcn_mfma_f32_16x16x32_bf16(axx[i], b2[j], acc[i][j], 0, 0, 0);
            }

        __syncthreads();
    }

    unsigned short* ob = (which == 0) ? kb : (which == 1) ? vb : srb;
    const bool sig = (which == 2);
#pragma unroll
    for (int i = 0; i < 4; i++)
#pragma unroll
        for (int j = 0; j < 8; j++)
#pragma unroll
            for (int ii = 0; ii < 4; ii++) {
                const int m = m0 + wv * 64 + i * 16 + q * 4 + ii;
                const int n = nslab * 128 + j * 16 + l16;
                float val = acc[i][j][ii];
                if (sig) val = 1.0f / (1.0f + __expf(-val));
                ob[(size_t)m * CC + n] = f2bf(val);
            }
}

// ---------------------------------------------------------------------------
// WKV chunked parallel scan (unchanged).
// ---------------------------------------------------------------------------
__global__ __launch_bounds__(256) void wkv_part1(
    const unsigned short* __restrict__ kb, const unsigned short* __restrict__ vb,
    const float* __restrict__ sd,
    float* __restrict__ sp_, float* __restrict__ sq_, float* __restrict__ so_) {
    const int idx = blockIdx.x * 256 + threadIdx.x;
    const int c = idx & (CC - 1);
    const int b = (idx >> 9) & (BB - 1);
    const int s = idx >> 12;
    const float w = sd[c] * (1.0f / (float)TT);
    const size_t base = ((size_t)b * TT + (size_t)s * LL) * CC + c;
    const unsigned short* kp = kb + base;
    const unsigned short* vp = vb + base;

    float p = 0.f, q = 0.f, o = -1e38f;
#pragma unroll 8
    for (int i = 0; i < LL; ++i) {
        const float kt = bf2f(kp[(size_t)i * CC]);
        const float vt = bf2f(vp[(size_t)i * CC]);
        const float no2 = fmaxf(w + o, kt);
        const float A2  = __expf(w + o - no2);
        const float B2  = __expf(kt - no2);
        p = A2 * p + B2 * vt;
        q = A2 * q + B2;
        o = no2;
    }
    sp_[idx] = p; sq_[idx] = q; so_[idx] = o;
}

__global__ __launch_bounds__(256) void wkv_part2(
    const float* __restrict__ sd,
    float* __restrict__ sp_, float* __restrict__ sq_, float* __restrict__ so_) {
    const int idx = blockIdx.x * 256 + threadIdx.x;
    const int c = idx & (CC - 1);
    const float wL = sd[c] * ((float)LL / (float)TT);

    float p = 0.f, q = 0.f, o = -1e38f;
    float lp = sp_[idx], lq = sq_[idx], lo = so_[idx];
    for (int s = 0; s < SS; ++s) {
        const int off = s * (BB * CC) + idx;
        float nlp = 0.f, nlq = 0.f, nlo = 0.f;
        if (s + 1 < SS) {
            nlp = sp_[off + BB * CC];
            nlq = sq_[off + BB * CC];
            nlo = so_[off + BB * CC];
        }
        sp_[off] = p; sq_[off] = q; so_[off] = o;
        const float no = fmaxf(o + wL, lo);
        const float A  = __expf(o + wL - no);
        const float Bc = __expf(lo - no);
        p = A * p + Bc * lp;
        q = A * q + Bc * lq;
        o = no;
        lp = nlp; lq = nlq; lo = nlo;
    }
}

__global__ __launch_bounds__(256) void wkv_part3(
    const unsigned short* __restrict__ kb, const unsigned short* __restrict__ vb,
    unsigned short* __restrict__ srz,
    const float* __restrict__ sd, const float* __restrict__ sf,
    const float* __restrict__ sp_, const float* __restrict__ sq_,
    const float* __restrict__ so_) {
    const int idx = blockIdx.x * 256 + threadIdx.x;
    const int c = idx & (CC - 1);
    const int b = (idx >> 9) & (BB - 1);
    const int s = idx >> 12;
    const float w = sd[c] * (1.0f / (float)TT);
    const float u = sf[c] * (1.0f / (float)TT);
    const size_t base = ((size_t)b * TT + (size_t)s * LL) * CC + c;
    const unsigned short* kp = kb + base;
    const unsigned short* vp = vb + base;
    unsigned short* sp = srz + base;

    float p = sp_[idx], q = sq_[idx], o = so_[idx];
#pragma unroll 4
    for (int i = 0; i < LL; ++i) {
        const float kt = bf2f(kp[(size_t)i * CC]);
        const float vt = bf2f(vp[(size_t)i * CC]);
        const float sr = bf2f(sp[(size_t)i * CC]);

        const float no = fmaxf(o, u + kt);
        const float A  = __expf(o - no);
        const float Bt = __expf(u + kt - no);
        const float y  = (A * p + Bt * vt) / (A * q + Bt);
        sp[(size_t)i * CC] = f2bf(sr * y);

        const float no2 = fmaxf(w + o, kt);
        const float A2  = __expf(w + o - no2);
        const float B2  = __expf(kt - no2);
        p = A2 * p + B2 * vt;
        q = A2 * q + B2;
        o = no2;
    }
}

// ---------------------------------------------------------------------------
// Kernel 4: out = z @ wo (fp32 out)
// ---------------------------------------------------------------------------
__global__ __launch_bounds__(256, 2) void gemm_out(
    const unsigned short* __restrict__ zb, const unsigned short* __restrict__ woT,
    float* __restrict__ out) {
    __shared__ unsigned short As[128 * 32];
    __shared__ unsigned short Bs[128 * 32];

    const int tid = threadIdx.x;
    const int pn = blockIdx.x, pm = blockIdx.y;

    const int r0 = tid >> 2;
    const int cc = (tid & 3) * 8;
    const unsigned short* ag0 = zb + (size_t)(pm * 128 + r0) * CC + cc;
    const unsigned short* ag1 = ag0 + (size_t)64 * CC;
    const unsigned short* bg0 = woT + (size_t)(pn * 128 + r0) * CC + cc;
    const unsigned short* bg1 = bg0 + (size_t)64 * CC;
    unsigned short* al0 = &As[tid * 8];
    unsigned short* al1 = &As[2048 + tid * 8];
    unsigned short* bl0 = &Bs[tid * 8];
    unsigned short* bl1 = &Bs[2048 + tid * 8];

    const int wave = tid >> 6, lane = tid & 63;
    const int wr_ = wave >> 1, wc_ = wave & 1;
    const int q = lane >> 4, l16 = lane & 15;

    f32x4 acc[4][4];
#pragma unroll
    for (int i = 0; i < 4; i++)
#pragma unroll
        for (int j = 0; j < 4; j++) acc[i][j] = (f32x4){0.f, 0.f, 0.f, 0.f};

    for (int kt = 0; kt < 16; ++kt) {
        const int k0 = kt * 32;
        gl_lds16(ag0 + k0, al0);
        gl_lds16(ag1 + k0, al1);
        gl_lds16(bg0 + k0, bl0);
        gl_lds16(bg1 + k0, bl1);

        __syncthreads();

        short8 a[4], b[4];
#pragma unroll
        for (int i = 0; i < 4; i++)
            a[i] = *(const short8*)&As[(wr_ * 64 + i * 16 + l16) * 32 + q * 8];
#pragma unroll
        for (int j = 0; j < 4; j++)
            b[j] = *(const short8*)&Bs[(wc_ * 64 + j * 16 + l16) * 32 + q * 8];
#pragma unroll
        for (int i = 0; i < 4; i++)
#pragma unroll
            for (int j = 0; j < 4; j++)
                acc[i][j] = __builtin_amdgcn_mfma_f32_16x16x32_bf16(a[i], b[j], acc[i][j], 0, 0, 0);

        __syncthreads();
    }

    const int gm0 = pm * 128 + wr_ * 64;
    const int gn0 = pn * 128 + wc_ * 64;
#pragma unroll
    for (int i = 0; i < 4; i++)
#pragma unroll
        for (int j = 0; j < 4; j++)
#pragma unroll
            for (int ii = 0; ii < 4; ii++) {
                const int m = gm0 + i * 16 + q * 4 + ii;
                const int n = gn0 + j * 16 + l16;
                out[(size_t)m * CC + n] = acc[i][j][ii];
            }
}

// ---------------------------------------------------------------------------
extern "C" void kernel_launch(void* const* d_in, const int* in_sizes, int n_in,
                              void* d_out, int out_size, void* d_ws, size_t ws_size,
                              hipStream_t stream) {
    const float* x  = (const float*)d_in[0];
    const float* sd = (const float*)d_in[1];
    const float* sf = (const float*)d_in[2];
    const float* mk = (const float*)d_in[3];
    const float* mv = (const float*)d_in[4];
    const float* mr = (const float*)d_in[5];
    const float* wk = (const float*)d_in[6];
    const float* wv = (const float*)d_in[7];
    const float* wr = (const float*)d_in[8];
    const float* wo = (const float*)d_in[9];
    float* out = (float*)d_out;

    // ws layout (~138 MiB total; proven-safe ceiling 194 MiB):
    //   w1T bf16 [3][512][512]  1.5 MiB   (diag(m)  . w, transposed)
    //   w2T bf16 [3][512][512]  1.5 MiB   (diag(1-m). w, transposed)
    //   woT bf16 [512][512]     0.5 MiB
    //   zp  zero page           4 KiB
    //   xb  bf16 [M][C]         32 MiB
    //   kb / vb / srb(->z) bf16 [M][C]  3 x 32 MiB
    //   sp/sq/so fp32 [S][B][C] 3 x 2 MiB
    char* ws = (char*)d_ws;
    unsigned short* w1T = (unsigned short*)ws;
    unsigned short* w2T = w1T + (size_t)3 * CC * CC;
    unsigned short* woT = w2T + (size_t)3 * CC * CC;
    unsigned short* zp  = woT + (size_t)CC * CC;
    unsigned short* xb  = zp + 2048;
    unsigned short* kb  = xb + (size_t)MM * CC;
    unsigned short* vb  = kb + (size_t)MM * CC;
    unsigned short* srb = vb + (size_t)MM * CC;
    float* sp_ = (float*)(srb + (size_t)MM * CC);
    float* sq_ = sp_ + (size_t)SS * BB * CC;
    float* so_ = sq_ + (size_t)SS * BB * CC;

    prep<<<dim3(NXB + NWB + NOB + 1), 256, 0, stream>>>(
        x, mk, mv, mr, wk, wv, wr, wo, xb, w1T, w2T, woT, zp);

    gemm_kvr3<<<dim3(128, 12), 256, 0, stream>>>(xb, w1T, w2T, zp, kb, vb, srb);

    wkv_part1<<<dim3((SS * BB * CC) / 256), 256, 0, stream>>>(kb, vb, sd, sp_, sq_, so_);
    wkv_part2<<<dim3((BB * CC) / 256), 256, 0, stream>>>(sd, sp_, sq_, so_);
    wkv_part3<<<dim3((SS * BB * CC) / 256), 256, 0, stream>>>(
        kb, vb, srb, sd, sf, sp_, sq_, so_);

    gemm_out<<<dim3(4, MM / 128), 256, 0, stream>>>(srb, woT, out);
}